// Round 11
// baseline (398.214 us; speedup 1.0000x reference)
//
#include <hip/hip_runtime.h>
#include <stdint.h>

#define N_NODES 100000
#define E_EDGES 600000
#define IN_F    128
#define HID_F   256
#define OUT_F   128
#define NB_SCAN 98   // ceil(N_NODES / 1024)

typedef unsigned short ushort_t;
typedef short  short8  __attribute__((ext_vector_type(8)));
typedef float  floatx4 __attribute__((ext_vector_type(4)));

__device__ __forceinline__ float bf2f(unsigned u16) {
    return __uint_as_float(u16 << 16);
}
__device__ __forceinline__ ushort_t f2bf(float f) {
    unsigned u = __float_as_uint(f);
    return (ushort_t)((u + 0x7fffu + ((u >> 16) & 1u)) >> 16);   // RNE
}

// ---- fused prep: x fp32->bf16 cast + 4 weight transposes + cursor zeroing ---
// Zeroes sentinel rows (index N_NODES) of xbf (agg128 input) and P (agg256
// input = h1) so gather kernels clamp out-of-range edge slots to a zero row.
__global__ void k_prep(const float* __restrict__ x, ushort_t* __restrict__ xbf,
                       const float* __restrict__ W1a, const float* __restrict__ W1b,
                       const float* __restrict__ W2a, const float* __restrict__ W2b,
                       ushort_t* __restrict__ WT1a, ushort_t* __restrict__ WT1b,
                       ushort_t* __restrict__ WT2a, ushort_t* __restrict__ WT2b,
                       int* __restrict__ cursor, ushort_t* __restrict__ P) {
    int t = blockIdx.x * 256 + threadIdx.x;
    if (t < N_NODES * IN_F / 2) {
        float2 v = ((const float2*)x)[t];
        ((unsigned*)xbf)[t] = (unsigned)f2bf(v.x) | ((unsigned)f2bf(v.y) << 16);
    }
    if (t < N_NODES) cursor[t] = 0;
    if (t < 128) ((unsigned*)(P + (size_t)N_NODES * HID_F))[t] = 0;   // P sentinel row
    if (t < 64)  ((unsigned*)(xbf + (size_t)N_NODES * IN_F))[t] = 0;  // xbf sentinel row
    if (t < 32768) {
        int k = t >> 8, n = t & 255;
        WT1a[n * 128 + k] = f2bf(W1a[t]);
    } else if (t < 98304) {
        int i = t - 32768, k = i >> 8, n = i & 255;
        WT1b[n * 256 + k] = f2bf(W1b[i]);
    } else if (t < 163840) {
        int i = t - 98304, k = i >> 8, n = i & 255;
        WT2a[n * 256 + k] = f2bf(W2a[i]);
    } else if (t < 196608) {
        int i = t - 163840, k = i >> 7, n = i & 127;
        WT2b[n * 256 + k] = f2bf(W2b[i]);
    }
}

// ---------------- CSR build --------------------------------------------------
__global__ void k_hist(const int* __restrict__ dst, int* __restrict__ deg) {
    int e = blockIdx.x * 256 + threadIdx.x;
    if (e < E_EDGES) atomicAdd(&deg[dst[e]], 1);
}

__global__ void k_scan1(const int* __restrict__ deg, int* __restrict__ row_ptr,
                        int* __restrict__ psum) {
    __shared__ int s[1024];
    int t = threadIdx.x, i = blockIdx.x * 1024 + t;
    int v = (i < N_NODES) ? deg[i] : 0;
    s[t] = v;
    __syncthreads();
    for (int off = 1; off < 1024; off <<= 1) {
        int u = (t >= off) ? s[t - off] : 0;
        __syncthreads();
        if (t >= off) s[t] += u;
        __syncthreads();
    }
    if (i < N_NODES) row_ptr[i] = s[t] - v;          // exclusive within block
    if (t == 1023) psum[blockIdx.x] = s[t];          // block total
}

// scan3 folds the former scan2: each block reduces psum[0..bid) in LDS
// (98 ints, no cross-block communication) to get its exclusive offset.
__global__ void k_scan3(int* __restrict__ row_ptr, const int* __restrict__ psum,
                        int* __restrict__ cursor) {
    __shared__ int pr[128];
    int t = threadIdx.x;
    if (t < 128) pr[t] = (t < blockIdx.x && t < NB_SCAN) ? psum[t] : 0;
    __syncthreads();
    for (int off = 64; off > 0; off >>= 1) {
        if (t < off) pr[t] += pr[t + off];
        __syncthreads();
    }
    const int pre = pr[0];
    int i = blockIdx.x * 1024 + t;
    if (i < N_NODES) {
        int r = row_ptr[i] + pre;
        row_ptr[i] = r;
        cursor[i]  = r;
    }
    if (i == 0) row_ptr[N_NODES] = E_EDGES;
}

__global__ void k_fill(const int* __restrict__ src, const int* __restrict__ dst,
                       int* __restrict__ cursor, int* __restrict__ colidx) {
    int e = blockIdx.x * 256 + threadIdx.x;
    if (e < E_EDGES) {
        int pos = atomicAdd(&cursor[dst[e]], 1);
        colidx[pos] = src[e];
    }
}

// ---- gather aggregation L1: 4 edges in flight per wave (quarter-split) ------
__global__ void k_agg128(const ushort_t* __restrict__ Xbf, const int* __restrict__ row_ptr,
                         const int* __restrict__ colidx, ushort_t* __restrict__ Out) {
    int node = blockIdx.x * 4 + (threadIdx.x >> 6);
    int lane = threadIdx.x & 63;
    int q = lane >> 4, l4 = lane & 15;
    const uint4* xr = (const uint4*)Xbf;              // 16 uint4 per row
    uint4 u = xr[(size_t)node * 16 + l4];
    float a0 = q ? 0.f : bf2f(u.x & 0xffffu);
    float a1 = q ? 0.f : bf2f(u.x >> 16);
    float a2 = q ? 0.f : bf2f(u.y & 0xffffu);
    float a3 = q ? 0.f : bf2f(u.y >> 16);
    float a4 = q ? 0.f : bf2f(u.z & 0xffffu);
    float a5 = q ? 0.f : bf2f(u.z >> 16);
    float a6 = q ? 0.f : bf2f(u.w & 0xffffu);
    float a7 = q ? 0.f : bf2f(u.w >> 16);
    int r0 = row_ptr[node], r1 = row_ptr[node + 1];
    for (int base = r0 + q; base < r1; base += 8) {
        int j0 = colidx[base];                        // always valid (base < r1)
        int j1 = colidx[min(base + 4, r1 - 1)];
        j1 = (base + 4 < r1) ? j1 : N_NODES;          // sentinel = zero row
        uint4 w0 = xr[(size_t)j0 * 16 + l4];
        uint4 w1 = xr[(size_t)j1 * 16 + l4];
        a0 += bf2f(w0.x & 0xffffu) + bf2f(w1.x & 0xffffu);
        a1 += bf2f(w0.x >> 16)     + bf2f(w1.x >> 16);
        a2 += bf2f(w0.y & 0xffffu) + bf2f(w1.y & 0xffffu);
        a3 += bf2f(w0.y >> 16)     + bf2f(w1.y >> 16);
        a4 += bf2f(w0.z & 0xffffu) + bf2f(w1.z & 0xffffu);
        a5 += bf2f(w0.z >> 16)     + bf2f(w1.z >> 16);
        a6 += bf2f(w0.w & 0xffffu) + bf2f(w1.w & 0xffffu);
        a7 += bf2f(w0.w >> 16)     + bf2f(w1.w >> 16);
    }
    a0 += __shfl_xor(a0, 16, 64); a0 += __shfl_xor(a0, 32, 64);
    a1 += __shfl_xor(a1, 16, 64); a1 += __shfl_xor(a1, 32, 64);
    a2 += __shfl_xor(a2, 16, 64); a2 += __shfl_xor(a2, 32, 64);
    a3 += __shfl_xor(a3, 16, 64); a3 += __shfl_xor(a3, 32, 64);
    a4 += __shfl_xor(a4, 16, 64); a4 += __shfl_xor(a4, 32, 64);
    a5 += __shfl_xor(a5, 16, 64); a5 += __shfl_xor(a5, 32, 64);
    a6 += __shfl_xor(a6, 16, 64); a6 += __shfl_xor(a6, 32, 64);
    a7 += __shfl_xor(a7, 16, 64); a7 += __shfl_xor(a7, 32, 64);
    if (q == 0) {
        uint4 o;
        o.x = (unsigned)f2bf(a0) | ((unsigned)f2bf(a1) << 16);
        o.y = (unsigned)f2bf(a2) | ((unsigned)f2bf(a3) << 16);
        o.z = (unsigned)f2bf(a4) | ((unsigned)f2bf(a5) << 16);
        o.w = (unsigned)f2bf(a6) | ((unsigned)f2bf(a7) << 16);
        ((uint4*)Out)[(size_t)node * 16 + l4] = o;
    }
}

// ---- gather aggregation L2: 8 edges in flight per wave (half-split x4) ------
__global__ void k_agg256(const ushort_t* __restrict__ X, const int* __restrict__ row_ptr,
                         const int* __restrict__ colidx, ushort_t* __restrict__ Out) {
    int node = blockIdx.x * 4 + (threadIdx.x >> 6);
    int lane = threadIdx.x & 63;
    int h = lane >> 5, l5 = lane & 31;
    const uint4* xr = (const uint4*)X;                // 32 uint4 per row
    uint4 u = xr[(size_t)node * 32 + l5];
    float a0 = h ? 0.f : bf2f(u.x & 0xffffu);
    float a1 = h ? 0.f : bf2f(u.x >> 16);
    float a2 = h ? 0.f : bf2f(u.y & 0xffffu);
    float a3 = h ? 0.f : bf2f(u.y >> 16);
    float a4 = h ? 0.f : bf2f(u.z & 0xffffu);
    float a5 = h ? 0.f : bf2f(u.z >> 16);
    float a6 = h ? 0.f : bf2f(u.w & 0xffffu);
    float a7 = h ? 0.f : bf2f(u.w >> 16);
    int r0 = row_ptr[node], r1 = row_ptr[node + 1];
    for (int base = r0 + h; base < r1; base += 8) {
        int j0 = colidx[base];                        // always valid
        int j1 = colidx[min(base + 2, r1 - 1)];
        int j2 = colidx[min(base + 4, r1 - 1)];
        int j3 = colidx[min(base + 6, r1 - 1)];
        j1 = (base + 2 < r1) ? j1 : N_NODES;
        j2 = (base + 4 < r1) ? j2 : N_NODES;
        j3 = (base + 6 < r1) ? j3 : N_NODES;
        uint4 w0 = xr[(size_t)j0 * 32 + l5];
        uint4 w1 = xr[(size_t)j1 * 32 + l5];
        uint4 w2 = xr[(size_t)j2 * 32 + l5];
        uint4 w3 = xr[(size_t)j3 * 32 + l5];
        a0 += (bf2f(w0.x & 0xffffu) + bf2f(w1.x & 0xffffu)) +
              (bf2f(w2.x & 0xffffu) + bf2f(w3.x & 0xffffu));
        a1 += (bf2f(w0.x >> 16) + bf2f(w1.x >> 16)) +
              (bf2f(w2.x >> 16) + bf2f(w3.x >> 16));
        a2 += (bf2f(w0.y & 0xffffu) + bf2f(w1.y & 0xffffu)) +
              (bf2f(w2.y & 0xffffu) + bf2f(w3.y & 0xffffu));
        a3 += (bf2f(w0.y >> 16) + bf2f(w1.y >> 16)) +
              (bf2f(w2.y >> 16) + bf2f(w3.y >> 16));
        a4 += (bf2f(w0.z & 0xffffu) + bf2f(w1.z & 0xffffu)) +
              (bf2f(w2.z & 0xffffu) + bf2f(w3.z & 0xffffu));
        a5 += (bf2f(w0.z >> 16) + bf2f(w1.z >> 16)) +
              (bf2f(w2.z >> 16) + bf2f(w3.z >> 16));
        a6 += (bf2f(w0.w & 0xffffu) + bf2f(w1.w & 0xffffu)) +
              (bf2f(w2.w & 0xffffu) + bf2f(w3.w & 0xffffu));
        a7 += (bf2f(w0.w >> 16) + bf2f(w1.w >> 16)) +
              (bf2f(w2.w >> 16) + bf2f(w3.w >> 16));
    }
    a0 += __shfl_xor(a0, 32, 64);
    a1 += __shfl_xor(a1, 32, 64);
    a2 += __shfl_xor(a2, 32, 64);
    a3 += __shfl_xor(a3, 32, 64);
    a4 += __shfl_xor(a4, 32, 64);
    a5 += __shfl_xor(a5, 32, 64);
    a6 += __shfl_xor(a6, 32, 64);
    a7 += __shfl_xor(a7, 32, 64);
    if (h == 0) {
        uint4 o;
        o.x = (unsigned)f2bf(a0) | ((unsigned)f2bf(a1) << 16);
        o.y = (unsigned)f2bf(a2) | ((unsigned)f2bf(a3) << 16);
        o.z = (unsigned)f2bf(a4) | ((unsigned)f2bf(a5) << 16);
        o.w = (unsigned)f2bf(a6) | ((unsigned)f2bf(a7) << 16);
        ((uint4*)Out)[(size_t)node * 32 + l5] = o;
    }
}

// ---------------- GEMM: Out = relu(Act[nRows x FIN] @ W + b) -----------------
// Round-10 body with ONE change: the 128-col W-slab is staged in two 64-col
// halves through a single 32KB buffer (stage h0 -> barrier -> full-K MFMA for
// cols 0-63 -> barrier -> stage h1 -> barrier -> MFMA cols 64-127). LDS drops
// 64 -> 34.8KB (epilogue buffer is now the max) => 4 blocks/CU, 32 waves/CU,
// all 784 blocks co-resident in one scheduling round (was 2 blocks/CU, 1.53
// rounds, Occupancy 26%). Per-element K-accumulation order is unchanged
// (bit-identical numerics). A-fragments are re-read for the second half
// (L1/L2-hot, 16KB/wave). XCD pairing + coalesced epilogue unchanged.
template <int FIN, int FOUT, bool OUT_F32>
__global__ __launch_bounds__(512, 4) void gemm_relu(
    const ushort_t* __restrict__ Act, const ushort_t* __restrict__ WT,
    const float* __restrict__ bias, void* __restrict__ Out, int nRows)
{
    constexpr int CPR = FIN / 8;                  // 16B chunks per W row
    constexpr int KC  = FIN / 32;                 // k-chunks (4 or 8)
    constexpr int KP  = KC / 2;                   // chunk-pairs
    constexpr int SW  = 136;                      // epilogue LDS stride (ushorts)
    constexpr int WHE = 64 * FIN;                 // W half-slab elems (<=32KB)
    constexpr int EPE = 128 * SW;                 // epilogue elems (17408)
    constexpr int LDSE = OUT_F32 ? WHE : ((WHE > EPE) ? WHE : EPE);
    __shared__ ushort_t wt[LDSE];

    const int tid  = threadIdx.x;
    const int bid  = blockIdx.x;

    int rowblk, sl;
    if (FOUT == 256) {
        const int group = bid >> 4, w = bid & 15;
        rowblk = group * 8 + (w & 7);
        sl     = w >> 3;
        if (rowblk >= (nRows + 255) / 256) return;   // uniform per block: safe
    } else {
        rowblk = bid;
        sl     = 0;
    }
    const int slab = sl * 128;

    const int wave = tid >> 6, lane = tid & 63;
    const int quad = lane >> 4, l15 = lane & 15;
    const int rowBase = rowblk * 256 + wave * 32;

    int r0 = rowBase + l15;
    int r1 = r0 + 16;
    r0 = (r0 < nRows) ? r0 : (nRows - 1);
    r1 = (r1 < nRows) ? r1 : (nRows - 1);
    const ushort_t* a0p = Act + (size_t)r0 * FIN + quad * 8;
    const ushort_t* a1p = Act + (size_t)r1 * FIN + quad * 8;

    floatx4 acc[2][8];
#pragma unroll
    for (int mt = 0; mt < 2; ++mt)
#pragma unroll
        for (int nt = 0; nt < 8; ++nt)
#pragma unroll
            for (int r = 0; r < 4; ++r) acc[mt][nt][r] = 0.f;

#pragma unroll
    for (int hs = 0; hs < 2; ++hs) {
        if (hs) __syncthreads();   // all waves done reading wt half-0

        // stage 64-col W half -> LDS via async global_load_lds (16B/lane).
        // Local col nl = global col - hs*64; (nl & 15) == (n & 15) since the
        // half offset is a multiple of 16, so the XOR swizzle key matches.
        {
            const ushort_t* wsrc = WT + (size_t)(slab + hs * 64) * FIN;
#pragma unroll
            for (int rr = 0; rr < (64 * CPR) / 512; ++rr) {
                int ci  = rr * 512 + tid;
                int nl  = ci / CPR;
                int csw = ci % CPR;
                int cor = csw ^ (nl & 15);
                const ushort_t* g = wsrc + (size_t)nl * FIN + cor * 8;
                __builtin_amdgcn_global_load_lds(
                    (const __attribute__((address_space(1))) unsigned*)g,
                    (__attribute__((address_space(3))) unsigned*)&wt[ci * 8],
                    16, 0, 0);
            }
        }

        // double-buffered A-fragments: [buf][m][kc], pair = 2 k-chunks
        short8 af[2][2][2];
#pragma unroll
        for (int kc = 0; kc < 2; ++kc) {
            af[0][0][kc] = *(const short8*)(a0p + kc * 32);
            af[0][1][kc] = *(const short8*)(a1p + kc * 32);
        }

        __syncthreads();   // drains global_load_lds (vmcnt) + all waves arrived

#pragma unroll
        for (int p = 0; p < KP; ++p) {
            const int cb = p & 1, nb = cb ^ 1;
            if (p + 1 < KP) {
#pragma unroll
                for (int kc = 0; kc < 2; ++kc) {
                    af[nb][0][kc] = *(const short8*)(a0p + ((p + 1) * 2 + kc) * 32);
                    af[nb][1][kc] = *(const short8*)(a1p + ((p + 1) * 2 + kc) * 32);
                }
            }
#pragma unroll
            for (int kc = 0; kc < 2; ++kc) {
                int chunk = (p * 2 + kc) * 4 + quad;
#pragma unroll
                for (int nt = 0; nt < 4; ++nt) {
                    int nl  = nt * 16 + l15;          // local col 0..63
                    int csw = chunk ^ (nl & 15);
                    short8 bfr = *(const short8*)&wt[nl * FIN + csw * 8];
                    acc[0][hs * 4 + nt] = __builtin_amdgcn_mfma_f32_16x16x32_bf16(af[cb][0][kc], bfr, acc[0][hs * 4 + nt], 0, 0, 0);
                    acc[1][hs * 4 + nt] = __builtin_amdgcn_mfma_f32_16x16x32_bf16(af[cb][1][kc], bfr, acc[1][hs * 4 + nt], 0, 0, 0);
                }
            }
        }
    }

    if (!OUT_F32) {
        // LDS-staged coalesced epilogue: per mt half (128 rows), stage relu'd
        // bf16 into padded LDS, then store uint4 rows (full 64B lines).
        // acc index j: colLocal = (j>>2)*64 + (j&3)*16 + l15.
        const int rowTileBase = rowblk * 256;
#pragma unroll
        for (int mt = 0; mt < 2; ++mt) {
            __syncthreads();   // mt=0: all waves done reading wt (half-1 MFMA);
                               // mt=1: all pass-0 LDS reads done
#pragma unroll
            for (int j = 0; j < 8; ++j) {
                int colLocal = (j >> 2) * 64 + (j & 3) * 16 + l15;
                int col = slab + colLocal;
                float bv = bias[col];
#pragma unroll
                for (int r = 0; r < 4; ++r) {
                    float v = fmaxf(acc[mt][j][r] + bv, 0.f);
                    wt[(wave * 16 + quad * 4 + r) * SW + colLocal] = f2bf(v);
                }
            }
            __syncthreads();
            // readback: 4 x (512 thr x 16B) = 128 rows x 256B
#pragma unroll
            for (int it = 0; it < 4; ++it) {
                int idx = it * 512 + tid;
                int gr  = idx >> 4;                 // 0..127 (staged row)
                int c   = idx & 15;                 // 16B chunk within row
                int row = rowTileBase + (gr >> 4) * 32 + mt * 16 + (gr & 15);
                uint4 vv = *(const uint4*)&wt[gr * SW + c * 8];
                if (row < nRows)
                    *(uint4*)((ushort_t*)Out + (size_t)row * FOUT + slab + c * 8) = vv;
            }
        }
    } else {
        // fp32 output: 4B/lane x 16 lanes = full 64B lines already
#pragma unroll
        for (int mt = 0; mt < 2; ++mt) {
#pragma unroll
            for (int j = 0; j < 8; ++j) {
                int col = slab + (j >> 2) * 64 + (j & 3) * 16 + l15;
                float bv = bias[col];
#pragma unroll
                for (int r = 0; r < 4; ++r) {
                    int row = rowBase + mt * 16 + quad * 4 + r;
                    if (row < nRows) {
                        float v = fmaxf(acc[mt][j][r] + bv, 0.f);
                        ((float*)Out)[(size_t)row * FOUT + col] = v;
                    }
                }
            }
        }
    }
}

extern "C" void kernel_launch(void* const* d_in, const int* in_sizes, int n_in,
                              void* d_out, int out_size, void* d_ws, size_t ws_size,
                              hipStream_t stream) {
    const float* x   = (const float*)d_in[0];
    const int*   ei  = (const int*)d_in[1];
    const int*   src = ei;
    const int*   dst = ei + E_EDGES;
    const float* W1a = (const float*)d_in[2];
    const float* b1a = (const float*)d_in[3];
    const float* W1b = (const float*)d_in[4];
    const float* b1b = (const float*)d_in[5];
    const float* W2a = (const float*)d_in[6];
    const float* b2a = (const float*)d_in[7];
    const float* W2b = (const float*)d_in[8];
    const float* b2b = (const float*)d_in[9];

    // workspace layout (~106 MB); P and Q carry one extra sentinel row
    const size_t NP1 = N_NODES + 1;
    ushort_t* P       = (ushort_t*)d_ws;                       // (N+1) x 256 bf16
    ushort_t* Q       = P + NP1 * HID_F;                       // (N+1) x 256 bf16
    ushort_t* xbf     = Q;   // x as bf16 ((N+1) x 128) — dead before Q is written
    int*      row_ptr = (int*)(Q + NP1 * HID_F);               // N+4 ints
    int*      cursor  = row_ptr + (N_NODES + 4);               // N ints
    int*      colidx  = cursor + N_NODES;                      // E ints
    int*      psum    = colidx + E_EDGES;                      // 128 ints
    ushort_t* WT1a    = (ushort_t*)(psum + 128);
    ushort_t* WT1b    = WT1a + 256 * 128;
    ushort_t* WT2a    = WT1b + 256 * 256;
    ushort_t* WT2b    = WT2a + 256 * 256;

    // fused x-cast + weight transpose + cursor zero + sentinel-row zero
    k_prep<<<(N_NODES * IN_F / 2 + 255) / 256, 256, 0, stream>>>(
        x, xbf, W1a, W1b, W2a, W2b, WT1a, WT1b, WT2a, WT2b, cursor, P);

    // CSR build (4 kernels; scan2 folded into scan3)
    k_hist <<<(E_EDGES + 255) / 256, 256, 0, stream>>>(dst, cursor);
    k_scan1<<<NB_SCAN, 1024, 0, stream>>>(cursor, row_ptr, psum);
    k_scan3<<<NB_SCAN, 1024, 0, stream>>>(row_ptr, psum, cursor);
    k_fill <<<(E_EDGES + 255) / 256, 256, 0, stream>>>(src, dst, cursor, colidx);

    const int ROWB = (N_NODES + 255) / 256;        // 391
    const int GP   = ((ROWB + 7) / 8) * 16;        // 784: XCD-paired grid (2 slabs)

    // layer 1: P := agg(xbf) [N x 128]; Q := relu(P@W1a+b1a); P := relu(Q@W1b+b1b) = h1
    k_agg128<<<N_NODES / 4, 256, 0, stream>>>(xbf, row_ptr, colidx, P);
    gemm_relu<128, 256, false><<<GP, 512, 0, stream>>>(P, WT1a, b1a, Q, N_NODES);
    gemm_relu<256, 256, false><<<GP, 512, 0, stream>>>(Q, WT1b, b1b, P, N_NODES);

    // layer 2: Q := agg(h1) [N x 256]; P := relu(Q@W2a+b2a); out := relu(P@W2b+b2b) fp32
    k_agg256<<<N_NODES / 4, 256, 0, stream>>>(P, row_ptr, colidx, Q);
    gemm_relu<256, 256, false><<<GP, 512, 0, stream>>>(Q, WT2a, b2a, P, N_NODES);
    gemm_relu<256, 128, true><<<ROWB, 512, 0, stream>>>(P, WT2b, b2b, d_out, N_NODES);
}

// Round 12
// 367.503 us; speedup vs baseline: 1.0836x; 1.0836x over previous
//
#include <hip/hip_runtime.h>
#include <stdint.h>

#define N_NODES 100000
#define E_EDGES 600000
#define IN_F    128
#define HID_F   256
#define OUT_F   128
#define NB_SCAN 98   // ceil(N_NODES / 1024)

typedef unsigned short ushort_t;
typedef short  short8  __attribute__((ext_vector_type(8)));
typedef float  floatx4 __attribute__((ext_vector_type(4)));

__device__ __forceinline__ float bf2f(unsigned u16) {
    return __uint_as_float(u16 << 16);
}
__device__ __forceinline__ ushort_t f2bf(float f) {
    unsigned u = __float_as_uint(f);
    return (ushort_t)((u + 0x7fffu + ((u >> 16) & 1u)) >> 16);   // RNE
}

// ---- fused prep: x fp32->bf16 cast + 4 weight transposes + cursor zeroing ---
// Zeroes sentinel rows (index N_NODES) of xbf (agg128 input) and P (agg256
// input = h1) so gather kernels clamp out-of-range edge slots to a zero row.
__global__ void k_prep(const float* __restrict__ x, ushort_t* __restrict__ xbf,
                       const float* __restrict__ W1a, const float* __restrict__ W1b,
                       const float* __restrict__ W2a, const float* __restrict__ W2b,
                       ushort_t* __restrict__ WT1a, ushort_t* __restrict__ WT1b,
                       ushort_t* __restrict__ WT2a, ushort_t* __restrict__ WT2b,
                       int* __restrict__ cursor, ushort_t* __restrict__ P) {
    int t = blockIdx.x * 256 + threadIdx.x;
    if (t < N_NODES * IN_F / 2) {
        float2 v = ((const float2*)x)[t];
        ((unsigned*)xbf)[t] = (unsigned)f2bf(v.x) | ((unsigned)f2bf(v.y) << 16);
    }
    if (t < N_NODES) cursor[t] = 0;
    if (t < 128) ((unsigned*)(P + (size_t)N_NODES * HID_F))[t] = 0;   // P sentinel row
    if (t < 64)  ((unsigned*)(xbf + (size_t)N_NODES * IN_F))[t] = 0;  // xbf sentinel row
    if (t < 32768) {
        int k = t >> 8, n = t & 255;
        WT1a[n * 128 + k] = f2bf(W1a[t]);
    } else if (t < 98304) {
        int i = t - 32768, k = i >> 8, n = i & 255;
        WT1b[n * 256 + k] = f2bf(W1b[i]);
    } else if (t < 163840) {
        int i = t - 98304, k = i >> 8, n = i & 255;
        WT2a[n * 256 + k] = f2bf(W2a[i]);
    } else if (t < 196608) {
        int i = t - 163840, k = i >> 7, n = i & 127;
        WT2b[n * 256 + k] = f2bf(W2b[i]);
    }
}

// ---------------- CSR build --------------------------------------------------
__global__ void k_hist(const int* __restrict__ dst, int* __restrict__ deg) {
    int e = blockIdx.x * 256 + threadIdx.x;
    if (e < E_EDGES) atomicAdd(&deg[dst[e]], 1);
}

__global__ void k_scan1(const int* __restrict__ deg, int* __restrict__ row_ptr,
                        int* __restrict__ psum) {
    __shared__ int s[1024];
    int t = threadIdx.x, i = blockIdx.x * 1024 + t;
    int v = (i < N_NODES) ? deg[i] : 0;
    s[t] = v;
    __syncthreads();
    for (int off = 1; off < 1024; off <<= 1) {
        int u = (t >= off) ? s[t - off] : 0;
        __syncthreads();
        if (t >= off) s[t] += u;
        __syncthreads();
    }
    if (i < N_NODES) row_ptr[i] = s[t] - v;          // exclusive within block
    if (t == 1023) psum[blockIdx.x] = s[t];          // block total
}

// scan3 folds the former scan2: each block reduces psum[0..bid) in LDS
// (98 ints, no cross-block communication) to get its exclusive offset.
__global__ void k_scan3(int* __restrict__ row_ptr, const int* __restrict__ psum,
                        int* __restrict__ cursor) {
    __shared__ int pr[128];
    int t = threadIdx.x;
    if (t < 128) pr[t] = (t < blockIdx.x && t < NB_SCAN) ? psum[t] : 0;
    __syncthreads();
    for (int off = 64; off > 0; off >>= 1) {
        if (t < off) pr[t] += pr[t + off];
        __syncthreads();
    }
    const int pre = pr[0];
    int i = blockIdx.x * 1024 + t;
    if (i < N_NODES) {
        int r = row_ptr[i] + pre;
        row_ptr[i] = r;
        cursor[i]  = r;
    }
    if (i == 0) row_ptr[N_NODES] = E_EDGES;
}

__global__ void k_fill(const int* __restrict__ src, const int* __restrict__ dst,
                       int* __restrict__ cursor, int* __restrict__ colidx) {
    int e = blockIdx.x * 256 + threadIdx.x;
    if (e < E_EDGES) {
        int pos = atomicAdd(&cursor[dst[e]], 1);
        colidx[pos] = src[e];
    }
}

// ---- gather aggregation L1: 4 edges in flight per wave (quarter-split) ------
__global__ void k_agg128(const ushort_t* __restrict__ Xbf, const int* __restrict__ row_ptr,
                         const int* __restrict__ colidx, ushort_t* __restrict__ Out) {
    int node = blockIdx.x * 4 + (threadIdx.x >> 6);
    int lane = threadIdx.x & 63;
    int q = lane >> 4, l4 = lane & 15;
    const uint4* xr = (const uint4*)Xbf;              // 16 uint4 per row
    uint4 u = xr[(size_t)node * 16 + l4];
    float a0 = q ? 0.f : bf2f(u.x & 0xffffu);
    float a1 = q ? 0.f : bf2f(u.x >> 16);
    float a2 = q ? 0.f : bf2f(u.y & 0xffffu);
    float a3 = q ? 0.f : bf2f(u.y >> 16);
    float a4 = q ? 0.f : bf2f(u.z & 0xffffu);
    float a5 = q ? 0.f : bf2f(u.z >> 16);
    float a6 = q ? 0.f : bf2f(u.w & 0xffffu);
    float a7 = q ? 0.f : bf2f(u.w >> 16);
    int r0 = row_ptr[node], r1 = row_ptr[node + 1];
    for (int base = r0 + q; base < r1; base += 8) {
        int j0 = colidx[base];                        // always valid (base < r1)
        int j1 = colidx[min(base + 4, r1 - 1)];
        j1 = (base + 4 < r1) ? j1 : N_NODES;          // sentinel = zero row
        uint4 w0 = xr[(size_t)j0 * 16 + l4];
        uint4 w1 = xr[(size_t)j1 * 16 + l4];
        a0 += bf2f(w0.x & 0xffffu) + bf2f(w1.x & 0xffffu);
        a1 += bf2f(w0.x >> 16)     + bf2f(w1.x >> 16);
        a2 += bf2f(w0.y & 0xffffu) + bf2f(w1.y & 0xffffu);
        a3 += bf2f(w0.y >> 16)     + bf2f(w1.y >> 16);
        a4 += bf2f(w0.z & 0xffffu) + bf2f(w1.z & 0xffffu);
        a5 += bf2f(w0.z >> 16)     + bf2f(w1.z >> 16);
        a6 += bf2f(w0.w & 0xffffu) + bf2f(w1.w & 0xffffu);
        a7 += bf2f(w0.w >> 16)     + bf2f(w1.w >> 16);
    }
    a0 += __shfl_xor(a0, 16, 64); a0 += __shfl_xor(a0, 32, 64);
    a1 += __shfl_xor(a1, 16, 64); a1 += __shfl_xor(a1, 32, 64);
    a2 += __shfl_xor(a2, 16, 64); a2 += __shfl_xor(a2, 32, 64);
    a3 += __shfl_xor(a3, 16, 64); a3 += __shfl_xor(a3, 32, 64);
    a4 += __shfl_xor(a4, 16, 64); a4 += __shfl_xor(a4, 32, 64);
    a5 += __shfl_xor(a5, 16, 64); a5 += __shfl_xor(a5, 32, 64);
    a6 += __shfl_xor(a6, 16, 64); a6 += __shfl_xor(a6, 32, 64);
    a7 += __shfl_xor(a7, 16, 64); a7 += __shfl_xor(a7, 32, 64);
    if (q == 0) {
        uint4 o;
        o.x = (unsigned)f2bf(a0) | ((unsigned)f2bf(a1) << 16);
        o.y = (unsigned)f2bf(a2) | ((unsigned)f2bf(a3) << 16);
        o.z = (unsigned)f2bf(a4) | ((unsigned)f2bf(a5) << 16);
        o.w = (unsigned)f2bf(a6) | ((unsigned)f2bf(a7) << 16);
        ((uint4*)Out)[(size_t)node * 16 + l4] = o;
    }
}

// ---- gather aggregation L2: 8 edges in flight per wave (half-split x4) ------
__global__ void k_agg256(const ushort_t* __restrict__ X, const int* __restrict__ row_ptr,
                         const int* __restrict__ colidx, ushort_t* __restrict__ Out) {
    int node = blockIdx.x * 4 + (threadIdx.x >> 6);
    int lane = threadIdx.x & 63;
    int h = lane >> 5, l5 = lane & 31;
    const uint4* xr = (const uint4*)X;                // 32 uint4 per row
    uint4 u = xr[(size_t)node * 32 + l5];
    float a0 = h ? 0.f : bf2f(u.x & 0xffffu);
    float a1 = h ? 0.f : bf2f(u.x >> 16);
    float a2 = h ? 0.f : bf2f(u.y & 0xffffu);
    float a3 = h ? 0.f : bf2f(u.y >> 16);
    float a4 = h ? 0.f : bf2f(u.z & 0xffffu);
    float a5 = h ? 0.f : bf2f(u.z >> 16);
    float a6 = h ? 0.f : bf2f(u.w & 0xffffu);
    float a7 = h ? 0.f : bf2f(u.w >> 16);
    int r0 = row_ptr[node], r1 = row_ptr[node + 1];
    for (int base = r0 + h; base < r1; base += 8) {
        int j0 = colidx[base];                        // always valid
        int j1 = colidx[min(base + 2, r1 - 1)];
        int j2 = colidx[min(base + 4, r1 - 1)];
        int j3 = colidx[min(base + 6, r1 - 1)];
        j1 = (base + 2 < r1) ? j1 : N_NODES;
        j2 = (base + 4 < r1) ? j2 : N_NODES;
        j3 = (base + 6 < r1) ? j3 : N_NODES;
        uint4 w0 = xr[(size_t)j0 * 32 + l5];
        uint4 w1 = xr[(size_t)j1 * 32 + l5];
        uint4 w2 = xr[(size_t)j2 * 32 + l5];
        uint4 w3 = xr[(size_t)j3 * 32 + l5];
        a0 += (bf2f(w0.x & 0xffffu) + bf2f(w1.x & 0xffffu)) +
              (bf2f(w2.x & 0xffffu) + bf2f(w3.x & 0xffffu));
        a1 += (bf2f(w0.x >> 16) + bf2f(w1.x >> 16)) +
              (bf2f(w2.x >> 16) + bf2f(w3.x >> 16));
        a2 += (bf2f(w0.y & 0xffffu) + bf2f(w1.y & 0xffffu)) +
              (bf2f(w2.y & 0xffffu) + bf2f(w3.y & 0xffffu));
        a3 += (bf2f(w0.y >> 16) + bf2f(w1.y >> 16)) +
              (bf2f(w2.y >> 16) + bf2f(w3.y >> 16));
        a4 += (bf2f(w0.z & 0xffffu) + bf2f(w1.z & 0xffffu)) +
              (bf2f(w2.z & 0xffffu) + bf2f(w3.z & 0xffffu));
        a5 += (bf2f(w0.z >> 16) + bf2f(w1.z >> 16)) +
              (bf2f(w2.z >> 16) + bf2f(w3.z >> 16));
        a6 += (bf2f(w0.w & 0xffffu) + bf2f(w1.w & 0xffffu)) +
              (bf2f(w2.w & 0xffffu) + bf2f(w3.w & 0xffffu));
        a7 += (bf2f(w0.w >> 16) + bf2f(w1.w >> 16)) +
              (bf2f(w2.w >> 16) + bf2f(w3.w >> 16));
    }
    a0 += __shfl_xor(a0, 32, 64);
    a1 += __shfl_xor(a1, 32, 64);
    a2 += __shfl_xor(a2, 32, 64);
    a3 += __shfl_xor(a3, 32, 64);
    a4 += __shfl_xor(a4, 32, 64);
    a5 += __shfl_xor(a5, 32, 64);
    a6 += __shfl_xor(a6, 32, 64);
    a7 += __shfl_xor(a7, 32, 64);
    if (h == 0) {
        uint4 o;
        o.x = (unsigned)f2bf(a0) | ((unsigned)f2bf(a1) << 16);
        o.y = (unsigned)f2bf(a2) | ((unsigned)f2bf(a3) << 16);
        o.z = (unsigned)f2bf(a4) | ((unsigned)f2bf(a5) << 16);
        o.w = (unsigned)f2bf(a6) | ((unsigned)f2bf(a7) << 16);
        ((uint4*)Out)[(size_t)node * 32 + l5] = o;
    }
}

// ---------------- GEMM: Out = relu(Act[nRows x FIN] @ W + b) -----------------
// Proven kernel (256x128 tile, 8 waves, pairwise A dbuf, LDS W slab via
// global_load_lds, XCD-paired grid for FOUT=256, LDS-staged coalesced bf16
// epilogue). Five structural rewrites of this skeleton regressed; do not
// change the {64KB stage -> 1 barrier -> 64 MFMA/wave -> epilogue} shape.
template <int FIN, int FOUT, bool OUT_F32>
__global__ __launch_bounds__(512, 4) void gemm_relu(
    const ushort_t* __restrict__ Act, const ushort_t* __restrict__ WT,
    const float* __restrict__ bias, void* __restrict__ Out, int nRows)
{
    constexpr int CPR = FIN / 8;                  // 16B chunks per LDS row
    constexpr int KC  = FIN / 32;                 // k-chunks (4 or 8)
    constexpr int KP  = KC / 2;                   // chunk-pairs
    constexpr int SW  = 136;                      // epilogue LDS stride (ushorts)
    constexpr int WTE = 128 * FIN;                // W-slab elems
    constexpr int EPE = 128 * SW;                 // epilogue elems (17408)
    __shared__ ushort_t wt[(WTE > EPE) ? WTE : EPE];

    const int tid  = threadIdx.x;
    const int bid  = blockIdx.x;

    int rowblk, sl;
    if (FOUT == 256) {
        const int group = bid >> 4, w = bid & 15;
        rowblk = group * 8 + (w & 7);
        sl     = w >> 3;
        if (rowblk >= (nRows + 255) / 256) return;   // uniform per block: safe
    } else {
        rowblk = bid;
        sl     = 0;
    }
    const int slab = sl * 128;

    // stage WT slab -> LDS via async global_load_lds (16B/lane).
    {
        const ushort_t* wsrc = WT + (size_t)slab * FIN;
#pragma unroll
        for (int rr = 0; rr < (128 * CPR) / 512; ++rr) {
            int ci  = rr * 512 + tid;
            int n   = ci / CPR;
            int csw = ci % CPR;
            int cor = csw ^ (n & 15);
            const ushort_t* g = wsrc + (size_t)n * FIN + cor * 8;
            __builtin_amdgcn_global_load_lds(
                (const __attribute__((address_space(1))) unsigned*)g,
                (__attribute__((address_space(3))) unsigned*)&wt[ci * 8],
                16, 0, 0);
        }
    }

    const int wave = tid >> 6, lane = tid & 63;
    const int quad = lane >> 4, l15 = lane & 15;
    const int rowBase = rowblk * 256 + wave * 32;

    int r0 = rowBase + l15;
    int r1 = r0 + 16;
    r0 = (r0 < nRows) ? r0 : (nRows - 1);
    r1 = (r1 < nRows) ? r1 : (nRows - 1);
    const ushort_t* a0p = Act + (size_t)r0 * FIN + quad * 8;
    const ushort_t* a1p = Act + (size_t)r1 * FIN + quad * 8;

    // double-buffered A-fragments: [buf][m][kc], pair = 2 k-chunks
    short8 af[2][2][2];
#pragma unroll
    for (int kc = 0; kc < 2; ++kc) {
        af[0][0][kc] = *(const short8*)(a0p + kc * 32);
        af[0][1][kc] = *(const short8*)(a1p + kc * 32);
    }

    floatx4 acc[2][8];
#pragma unroll
    for (int mt = 0; mt < 2; ++mt)
#pragma unroll
        for (int nt = 0; nt < 8; ++nt)
#pragma unroll
            for (int r = 0; r < 4; ++r) acc[mt][nt][r] = 0.f;

    __syncthreads();   // drains global_load_lds (vmcnt) + all waves arrived

#pragma unroll
    for (int p = 0; p < KP; ++p) {
        const int cb = p & 1, nb = cb ^ 1;
        if (p + 1 < KP) {
#pragma unroll
            for (int kc = 0; kc < 2; ++kc) {
                af[nb][0][kc] = *(const short8*)(a0p + ((p + 1) * 2 + kc) * 32);
                af[nb][1][kc] = *(const short8*)(a1p + ((p + 1) * 2 + kc) * 32);
            }
        }
#pragma unroll
        for (int kc = 0; kc < 2; ++kc) {
            int chunk = (p * 2 + kc) * 4 + quad;
#pragma unroll
            for (int nt = 0; nt < 8; ++nt) {
                int n = nt * 16 + l15;
                int csw = chunk ^ (n & 15);
                short8 bfr = *(const short8*)&wt[n * FIN + csw * 8];
                acc[0][nt] = __builtin_amdgcn_mfma_f32_16x16x32_bf16(af[cb][0][kc], bfr, acc[0][nt], 0, 0, 0);
                acc[1][nt] = __builtin_amdgcn_mfma_f32_16x16x32_bf16(af[cb][1][kc], bfr, acc[1][nt], 0, 0, 0);
            }
        }
    }

    if (!OUT_F32) {
        // LDS-staged coalesced epilogue: per mt half (128 rows), stage relu'd
        // bf16 into padded LDS, then store uint4 rows (full 64B lines).
        const int rowTileBase = rowblk * 256;
#pragma unroll
        for (int mt = 0; mt < 2; ++mt) {
            __syncthreads();   // mt=0: all waves done reading wt (MFMA);
                               // mt=1: all pass-0 LDS reads done
#pragma unroll
            for (int nt = 0; nt < 8; ++nt) {
                int col = slab + nt * 16 + l15;
                float bv = bias[col];
#pragma unroll
                for (int r = 0; r < 4; ++r) {
                    float v = fmaxf(acc[mt][nt][r] + bv, 0.f);
                    wt[(wave * 16 + quad * 4 + r) * SW + nt * 16 + l15] = f2bf(v);
                }
            }
            __syncthreads();
            // readback: 4 x (512 thr x 16B) = 128 rows x 256B
#pragma unroll
            for (int it = 0; it < 4; ++it) {
                int idx = it * 512 + tid;
                int gr  = idx >> 4;                 // 0..127 (staged row)
                int c   = idx & 15;                 // 16B chunk within row
                int row = rowTileBase + (gr >> 4) * 32 + mt * 16 + (gr & 15);
                uint4 vv = *(const uint4*)&wt[gr * SW + c * 8];
                if (row < nRows)
                    *(uint4*)((ushort_t*)Out + (size_t)row * FOUT + slab + c * 8) = vv;
            }
        }
    } else {
        // fp32 output: 4B/lane x 16 lanes = full 64B lines already
#pragma unroll
        for (int mt = 0; mt < 2; ++mt) {
#pragma unroll
            for (int nt = 0; nt < 8; ++nt) {
                int col = slab + nt * 16 + l15;
                float bv = bias[col];
#pragma unroll
                for (int r = 0; r < 4; ++r) {
                    int row = rowBase + mt * 16 + quad * 4 + r;
                    if (row < nRows) {
                        float v = fmaxf(acc[mt][nt][r] + bv, 0.f);
                        ((float*)Out)[(size_t)row * FOUT + col] = v;
                    }
                }
            }
        }
    }
}

extern "C" void kernel_launch(void* const* d_in, const int* in_sizes, int n_in,
                              void* d_out, int out_size, void* d_ws, size_t ws_size,
                              hipStream_t stream) {
    const float* x   = (const float*)d_in[0];
    const int*   ei  = (const int*)d_in[1];
    const int*   src = ei;
    const int*   dst = ei + E_EDGES;
    const float* W1a = (const float*)d_in[2];
    const float* b1a = (const float*)d_in[3];
    const float* W1b = (const float*)d_in[4];
    const float* b1b = (const float*)d_in[5];
    const float* W2a = (const float*)d_in[6];
    const float* b2a = (const float*)d_in[7];
    const float* W2b = (const float*)d_in[8];
    const float* b2b = (const float*)d_in[9];

    // workspace layout (~106 MB); P and Q carry one extra sentinel row
    const size_t NP1 = N_NODES + 1;
    ushort_t* P       = (ushort_t*)d_ws;                       // (N+1) x 256 bf16
    ushort_t* Q       = P + NP1 * HID_F;                       // (N+1) x 256 bf16
    ushort_t* xbf     = Q;   // x as bf16 ((N+1) x 128) — dead before Q is written
    int*      row_ptr = (int*)(Q + NP1 * HID_F);               // N+4 ints
    int*      cursor  = row_ptr + (N_NODES + 4);               // N ints
    int*      colidx  = cursor + N_NODES;                      // E ints
    int*      psum    = colidx + E_EDGES;                      // 128 ints
    ushort_t* WT1a    = (ushort_t*)(psum + 128);
    ushort_t* WT1b    = WT1a + 256 * 128;
    ushort_t* WT2a    = WT1b + 256 * 256;
    ushort_t* WT2b    = WT2a + 256 * 256;

    // fused x-cast + weight transpose + cursor zero + sentinel-row zero
    k_prep<<<(N_NODES * IN_F / 2 + 255) / 256, 256, 0, stream>>>(
        x, xbf, W1a, W1b, W2a, W2b, WT1a, WT1b, WT2a, WT2b, cursor, P);

    // CSR build (4 kernels; scan2 folded into scan3)
    k_hist <<<(E_EDGES + 255) / 256, 256, 0, stream>>>(dst, cursor);
    k_scan1<<<NB_SCAN, 1024, 0, stream>>>(cursor, row_ptr, psum);
    k_scan3<<<NB_SCAN, 1024, 0, stream>>>(row_ptr, psum, cursor);
    k_fill <<<(E_EDGES + 255) / 256, 256, 0, stream>>>(src, dst, cursor, colidx);

    const int ROWB = (N_NODES + 255) / 256;        // 391
    const int GP   = ((ROWB + 7) / 8) * 16;        // 784: XCD-paired grid (2 slabs)

    // layer 1: P := agg(xbf) [N x 128]; Q := relu(P@W1a+b1a); P := relu(Q@W1b+b1b) = h1
    k_agg128<<<N_NODES / 4, 256, 0, stream>>>(xbf, row_ptr, colidx, P);
    gemm_relu<128, 256, false><<<GP, 512, 0, stream>>>(P, WT1a, b1a, Q, N_NODES);
    gemm_relu<256, 256, false><<<GP, 512, 0, stream>>>(Q, WT1b, b1b, P, N_NODES);

    // layer 2: Q := agg(h1) [N x 256]; P := relu(Q@W2a+b2a); out := relu(P@W2b+b2b) fp32
    k_agg256<<<N_NODES / 4, 256, 0, stream>>>(P, row_ptr, colidx, Q);
    gemm_relu<256, 256, false><<<GP, 512, 0, stream>>>(Q, WT2a, b2a, P, N_NODES);
    gemm_relu<256, 128, true><<<ROWB, 512, 0, stream>>>(P, WT2b, b2b, d_out, N_NODES);
}